// Round 7
// baseline (1400.570 us; speedup 1.0000x reference)
//
#include <hip/hip_runtime.h>
#include <hip/hip_bf16.h>
#include <math.h>

// Problem constants
#define Bx  2
#define Nx  2048
#define Lx  1024
#define Kx  16
#define Hx  4
#define DHx 128
#define HDx 512

typedef unsigned short u16;
typedef unsigned int   u32;
typedef unsigned long long u64;

#define ALD 132   // padded leading dim for 128-wide fp32 LDS buffers (VALU path)
#define KLD 520   // padded leading dim for 512-wide fp32 LDS buffer (VALU path)

// MFMA path layout (u16 planes)
#define LDB  136  // u16 stride for 128-wide tiles (272B rows, 16B-aligned)

typedef __attribute__((ext_vector_type(8))) short bf16x8;
typedef __attribute__((ext_vector_type(4))) float f32x4;

__device__ __forceinline__ float bf(u16 v) { return __uint_as_float(((u32)v) << 16); }

__device__ __forceinline__ u16 f2bf(float f) {
  u32 u = __float_as_uint(f);
  u32 r = (u + 0x7fffu + ((u >> 16) & 1u)) >> 16;
  return (u16)r;
}

// split fp32 -> (hi, lo) bf16 pair; x ~= bf(hi) + bf(lo), rel err ~2^-17
__device__ __forceinline__ void split2(float v, u16* h, u16* l) {
  u16 hh = f2bf(v);
  *h = hh;
  *l = f2bf(v - bf(hh));
}

// -------- dtype-templated global loaders (ISB=1: bf16, ISB=0: fp32) --------
template <int ISB>
__device__ __forceinline__ float ldg1(const void* p, int i) {
  if (ISB) return bf(((const u16*)p)[i]);
  return ((const float*)p)[i];
}
template <int ISB>
__device__ __forceinline__ void ldg2(const void* p, int i, float& a, float& b) {
  if (ISB) {
    u32 u = *(const u32*)((const u16*)p + i);
    a = __uint_as_float(u << 16); b = __uint_as_float(u & 0xffff0000u);
  } else {
    float2 v = *(const float2*)((const float*)p + i);
    a = v.x; b = v.y;
  }
}
template <int ISB>
__device__ __forceinline__ void ldg4(const void* p, int i, float* o) {
  if (ISB) {
    uint2 u = *(const uint2*)((const u16*)p + i);
    o[0] = __uint_as_float(u.x << 16); o[1] = __uint_as_float(u.x & 0xffff0000u);
    o[2] = __uint_as_float(u.y << 16); o[3] = __uint_as_float(u.y & 0xffff0000u);
  } else {
    float4 v = *(const float4*)((const float*)p + i);
    o[0] = v.x; o[1] = v.y; o[2] = v.z; o[3] = v.w;
  }
}
template <int ISB>
__device__ __forceinline__ void ldg8(const void* p, int i, float* o) {
  if (ISB) {
    uint4 u = *(const uint4*)((const u16*)p + i);
    o[0] = __uint_as_float(u.x << 16); o[1] = __uint_as_float(u.x & 0xffff0000u);
    o[2] = __uint_as_float(u.y << 16); o[3] = __uint_as_float(u.y & 0xffff0000u);
    o[4] = __uint_as_float(u.z << 16); o[5] = __uint_as_float(u.z & 0xffff0000u);
    o[6] = __uint_as_float(u.w << 16); o[7] = __uint_as_float(u.w & 0xffff0000u);
  } else {
    float4 v0 = *(const float4*)((const float*)p + i);
    float4 v1 = *(const float4*)((const float*)p + i + 4);
    o[0] = v0.x; o[1] = v0.y; o[2] = v0.z; o[3] = v0.w;
    o[4] = v1.x; o[5] = v1.y; o[6] = v1.z; o[7] = v1.w;
  }
}
template <int ISB>
__device__ __forceinline__ void stg1(void* p, int i, float v) {
  if (ISB) ((u16*)p)[i] = f2bf(v);
  else ((float*)p)[i] = v;
}

__device__ __forceinline__ float geluf(float x) {
  // jax.nn.gelu approximate=True (tanh form)
  return 0.5f * x * (1.0f + tanhf(0.7978845608028654f * (x + 0.044715f * x * x * x)));
}

__device__ __forceinline__ u64 shfl_down_u64(u64 v, int off) {
  u32 lo = (u32)v, hi = (u32)(v >> 32);
  lo = __shfl_down(lo, off);
  hi = __shfl_down(hi, off);
  return (((u64)hi) << 32) | lo;
}

__device__ __forceinline__ u64 shfl_xor_u64(u64 v, int m) {
  u32 lo = (u32)v, hi = (u32)(v >> 32);
  lo = __shfl_xor(lo, m);
  hi = __shfl_xor(hi, m);
  return (((u64)hi) << 32) | lo;
}

// ---------------------------------------------------------------------------
// dtype sniffer: cls (layernorm scale) is all-ones. bf16 data -> 16/16 exact
// 1.0f when read as bf16; fp32 data -> alternating 0/1 (8/16) -> flag 0.
// Measured on this harness: flag==0 (inputs fp32; in_npz = 5.0 MB).
// ---------------------------------------------------------------------------
__global__ void k_sniff(const void* cls, int* flag) {
  if (threadIdx.x == 0) {
    int v = 0;
    for (int i = 0; i < 16; i++) {
      float a = bf(((const u16*)cls)[i]);
      if (a == 1.0f) v++;
    }
    *flag = (v == 16) ? 1 : 0;
  }
}

// ===========================================================================
// ==============  VALU PATH (kept for ISB=1 bf16 fallback)  =================
// ===========================================================================

template <int ISB>
__device__ __forceinline__ void gemm128(
    const float* __restrict__ in, const void* __restrict__ w, int ldw,
    const void* __restrict__ bias, float* __restrict__ out, int act, int t) {
  int cg = t & 63, j0 = cg * 2;
  int rg = t >> 6, r0 = rg * 4;
  float acc[4][2] = {};
  for (int i = 0; i < 128; i += 4) {
    float a[4][4];
#pragma unroll
    for (int rr = 0; rr < 4; rr++) {
      float4 v = *(const float4*)(in + (r0 + rr) * ALD + i);
      a[rr][0] = v.x; a[rr][1] = v.y; a[rr][2] = v.z; a[rr][3] = v.w;
    }
#pragma unroll
    for (int ii = 0; ii < 4; ii++) {
      float w0, w1;
      ldg2<ISB>(w, (i + ii) * ldw + j0, w0, w1);
#pragma unroll
      for (int rr = 0; rr < 4; rr++) {
        acc[rr][0] += a[rr][ii] * w0;
        acc[rr][1] += a[rr][ii] * w1;
      }
    }
  }
  float b0 = ldg1<ISB>(bias, j0), b1 = ldg1<ISB>(bias, j0 + 1);
#pragma unroll
  for (int rr = 0; rr < 4; rr++) {
    float v0 = acc[rr][0] + b0, v1 = acc[rr][1] + b1;
    if (act) { v0 = geluf(v0); v1 = geluf(v1); }
    out[(r0 + rr) * ALD + j0 + 0] = v0;
    out[(r0 + rr) * ALD + j0 + 1] = v1;
  }
}

template <int ISB>
__device__ __forceinline__ void gemm512(
    const float* __restrict__ in, const void* __restrict__ w,
    const void* __restrict__ bias, float* __restrict__ out, int t) {
  int cg = t & 127, j0 = cg * 4;
  int rg = t >> 7, r0 = rg * 8;
  float acc[8][4] = {};
  for (int i = 0; i < 128; i += 4) {
    float a[8][4];
#pragma unroll
    for (int rr = 0; rr < 8; rr++) {
      float4 v = *(const float4*)(in + (r0 + rr) * ALD + i);
      a[rr][0] = v.x; a[rr][1] = v.y; a[rr][2] = v.z; a[rr][3] = v.w;
    }
#pragma unroll
    for (int ii = 0; ii < 4; ii++) {
      float wv[4];
      ldg4<ISB>(w, (i + ii) * 512 + j0, wv);
#pragma unroll
      for (int rr = 0; rr < 8; rr++) {
        acc[rr][0] += a[rr][ii] * wv[0];
        acc[rr][1] += a[rr][ii] * wv[1];
        acc[rr][2] += a[rr][ii] * wv[2];
        acc[rr][3] += a[rr][ii] * wv[3];
      }
    }
  }
  float b0 = ldg1<ISB>(bias, j0), b1 = ldg1<ISB>(bias, j0 + 1);
  float b2 = ldg1<ISB>(bias, j0 + 2), b3 = ldg1<ISB>(bias, j0 + 3);
#pragma unroll
  for (int rr = 0; rr < 8; rr++) {
    float* op = out + (r0 + rr) * KLD + j0;
    op[0] = acc[rr][0] + b0;
    op[1] = acc[rr][1] + b1;
    op[2] = acc[rr][2] + b2;
    op[3] = acc[rr][3] + b3;
  }
}

template <int NV, int ISB>
__device__ __forceinline__ void ln_vecs(
    float* __restrict__ buf, int ld,
    const void* __restrict__ sc, const void* __restrict__ bi,
    float* __restrict__ scratch, float* __restrict__ ms, int t) {
  const int TPV = 256 / NV;
  const int EPV = 128 / TPV;
  int vec = t / TPV, seg = t % TPV;
  float s = 0.0f, s2 = 0.0f;
  float* bp = buf + vec * ld + seg * EPV;
#pragma unroll
  for (int e = 0; e < EPV; e++) { float xv = bp[e]; s += xv; s2 += xv * xv; }
  scratch[t] = s;
  scratch[256 + t] = s2;
  __syncthreads();
  if (t < NV) {
    float ss = 0.0f, ss2 = 0.0f;
    for (int e = 0; e < TPV; e++) { ss += scratch[t * TPV + e]; ss2 += scratch[256 + t * TPV + e]; }
    float m = ss * (1.0f / 128.0f);
    float var = fmaxf(ss2 * (1.0f / 128.0f) - m * m, 0.0f);
    ms[t * 2] = m;
    ms[t * 2 + 1] = rsqrtf(var + 1e-6f);
  }
  __syncthreads();
  float m = ms[vec * 2], rstd = ms[vec * 2 + 1];
#pragma unroll
  for (int e = 0; e < EPV; e++) {
    int col = seg * EPV + e;
    bp[e] = (bp[e] - m) * rstd * ldg1<ISB>(sc, col) + ldg1<ISB>(bi, col);
  }
}

template <int ISB>
__device__ __forceinline__ void ivw2_fuse(
    const float* __restrict__ in, const void* __restrict__ w,
    const void* __restrict__ bias, float* __restrict__ kv, int r0, int t) {
  int j0 = t * 2;
  float ag[8][2] = {}, ab[8][2] = {};
  for (int i = 0; i < 128; i += 4) {
    float a[8][4];
#pragma unroll
    for (int rr = 0; rr < 8; rr++) {
      float4 v = *(const float4*)(in + (r0 + rr) * ALD + i);
      a[rr][0] = v.x; a[rr][1] = v.y; a[rr][2] = v.z; a[rr][3] = v.w;
    }
#pragma unroll
    for (int ii = 0; ii < 4; ii++) {
      float g0, g1, b0, b1;
      ldg2<ISB>(w, (i + ii) * 1024 + j0, g0, g1);
      ldg2<ISB>(w, (i + ii) * 1024 + 512 + j0, b0, b1);
#pragma unroll
      for (int rr = 0; rr < 8; rr++) {
        ag[rr][0] += a[rr][ii] * g0; ag[rr][1] += a[rr][ii] * g1;
        ab[rr][0] += a[rr][ii] * b0; ab[rr][1] += a[rr][ii] * b1;
      }
    }
  }
  float bg0 = ldg1<ISB>(bias, j0), bg1 = ldg1<ISB>(bias, j0 + 1);
  float bb0 = ldg1<ISB>(bias, 512 + j0), bb1 = ldg1<ISB>(bias, 512 + j0 + 1);
#pragma unroll
  for (int rr = 0; rr < 8; rr++) {
    float* kp = kv + (r0 + rr) * KLD + j0;
    float v0 = kp[0], v1 = kp[1];
    kp[0] = v0 * (1.0f + (ag[rr][0] + bg0)) + (ab[rr][0] + bb0);
    kp[1] = v1 * (1.0f + (ag[rr][1] + bg1)) + (ab[rr][1] + bb1);
  }
}

template <int ISB>
__device__ __forceinline__ void mm_from_kv(
    const float* __restrict__ kv, const void* __restrict__ w,
    const void* __restrict__ bias, float* __restrict__ out, int vbase, int t) {
  int cg = t & 31, j0 = cg * 4;
  int vg = t >> 5, v0 = vg * 4;
  float acc[4][4] = {};
  for (int i = 0; i < 128; i += 4) {
    float a[4][4];
#pragma unroll
    for (int vi = 0; vi < 4; vi++) {
      int gv = vbase + v0 + vi;
      int r = gv >> 2, h = gv & 3;
      float4 v = *(const float4*)(kv + r * KLD + h * 128 + i);
      a[vi][0] = v.x; a[vi][1] = v.y; a[vi][2] = v.z; a[vi][3] = v.w;
    }
#pragma unroll
    for (int ii = 0; ii < 4; ii++) {
      float wv[4];
      ldg4<ISB>(w, (i + ii) * 128 + j0, wv);
#pragma unroll
      for (int vi = 0; vi < 4; vi++) {
        acc[vi][0] += a[vi][ii] * wv[0];
        acc[vi][1] += a[vi][ii] * wv[1];
        acc[vi][2] += a[vi][ii] * wv[2];
        acc[vi][3] += a[vi][ii] * wv[3];
      }
    }
  }
  float b0 = ldg1<ISB>(bias, j0), b1 = ldg1<ISB>(bias, j0 + 1);
  float b2 = ldg1<ISB>(bias, j0 + 2), b3 = ldg1<ISB>(bias, j0 + 3);
#pragma unroll
  for (int vi = 0; vi < 4; vi++) {
    float* op = out + (v0 + vi) * ALD + j0;
    op[0] = geluf(acc[vi][0] + b0);
    op[1] = geluf(acc[vi][1] + b1);
    op[2] = geluf(acc[vi][2] + b2);
    op[3] = geluf(acc[vi][3] + b3);
  }
}

template <int ISB>
__device__ __forceinline__ void mm_to_kv(
    const float* __restrict__ in, const void* __restrict__ w,
    const void* __restrict__ bias, float* __restrict__ kv, int vbase, int t) {
  int cg = t & 31, j0 = cg * 4;
  int vg = t >> 5, v0 = vg * 4;
  float acc[4][4] = {};
  for (int i = 0; i < 128; i += 4) {
    float a[4][4];
#pragma unroll
    for (int vi = 0; vi < 4; vi++) {
      float4 v = *(const float4*)(in + (v0 + vi) * ALD + i);
      a[vi][0] = v.x; a[vi][1] = v.y; a[vi][2] = v.z; a[vi][3] = v.w;
    }
#pragma unroll
    for (int ii = 0; ii < 4; ii++) {
      float wv[4];
      ldg4<ISB>(w, (i + ii) * 128 + j0, wv);
#pragma unroll
      for (int vi = 0; vi < 4; vi++) {
        acc[vi][0] += a[vi][ii] * wv[0];
        acc[vi][1] += a[vi][ii] * wv[1];
        acc[vi][2] += a[vi][ii] * wv[2];
        acc[vi][3] += a[vi][ii] * wv[3];
      }
    }
  }
  float b0 = ldg1<ISB>(bias, j0), b1 = ldg1<ISB>(bias, j0 + 1);
  float b2 = ldg1<ISB>(bias, j0 + 2), b3 = ldg1<ISB>(bias, j0 + 3);
#pragma unroll
  for (int vi = 0; vi < 4; vi++) {
    int gv = vbase + v0 + vi;
    int r = gv >> 2, h = gv & 3;
    float* op = kv + r * KLD + h * 128 + j0;
    op[0] = acc[vi][0] + b0;
    op[1] = acc[vi][1] + b1;
    op[2] = acc[vi][2] + b2;
    op[3] = acc[vi][3] + b3;
  }
}

struct SMEM {
  float CG[16 * ALD];
  float SA[32 * ALD];
  float KV[16 * KLD];
  float GV[128], BT[128];
  float INVS[32];
  float GWS[16];
  float ATT[64];
  float RED[256];
  float YV[512];
  int   IDX[16];
};

template <int ISB>
__global__ __launch_bounds__(256, 2) void k_fused(
    const void* __restrict__ x, const void* __restrict__ p,
    const void* __restrict__ c, const void* __restrict__ sig,
    const void* __restrict__ xh,
    const void* __restrict__ rffq, const void* __restrict__ rffv,
    const void* __restrict__ eqw1, const void* __restrict__ eqb1,
    const void* __restrict__ eqw2, const void* __restrict__ eqb2,
    const void* __restrict__ evw1, const void* __restrict__ evb1,
    const void* __restrict__ evw2, const void* __restrict__ evb2,
    const void* __restrict__ wq, const void* __restrict__ bq,
    const void* __restrict__ wk, const void* __restrict__ bk,
    const void* __restrict__ wv, const void* __restrict__ bv,
    const void* __restrict__ cw1, const void* __restrict__ cb1,
    const void* __restrict__ cls, const void* __restrict__ clb,
    const void* __restrict__ cw2, const void* __restrict__ cb2,
    const void* __restrict__ ivw1, const void* __restrict__ ivb1,
    const void* __restrict__ ivls, const void* __restrict__ ivlb,
    const void* __restrict__ ivw2, const void* __restrict__ ivb2,
    const void* __restrict__ mw1, const void* __restrict__ mb1,
    const void* __restrict__ mls, const void* __restrict__ mlb,
    const void* __restrict__ mw2, const void* __restrict__ mb2,
    const void* __restrict__ wo, const void* __restrict__ bo,
    const int* __restrict__ flag, void* __restrict__ outp) {
  if (*flag != ISB) return;
  __shared__ SMEM sm;
  __shared__ u64 WMIN[4];
  int t = threadIdx.x;
  int bid = blockIdx.x;
  int b = bid >> 11;
  float* bufA = sm.SA;
  float* bufB = sm.SA + 16 * ALD;

  float* DIST = sm.KV;
  float qx = ldg1<ISB>(x, bid * 2 + 0);
  float qy = ldg1<ISB>(x, bid * 2 + 1);
#pragma unroll
  for (int e = 0; e < 4; e++) {
    int l = t + e * 256;
    float px = ldg1<ISB>(p, (b * Lx + l) * 2 + 0);
    float py = ldg1<ISB>(p, (b * Lx + l) * 2 + 1);
    float dx = qx - px, dy = qy - py;
    float d2 = __fadd_rn(__fmul_rn(dx, dx), __fmul_rn(dy, dy));
    DIST[l] = __fsqrt_rn(d2);
  }
  __syncthreads();
  for (int kk = 0; kk < Kx; kk++) {
    u64 key = ~0ull;
#pragma unroll
    for (int e = 0; e < 4; e++) {
      int l = t + e * 256;
      u64 k2 = (((u64)__float_as_uint(DIST[l])) << 32) | (u32)l;
      key = key < k2 ? key : k2;
    }
#pragma unroll
    for (int off = 32; off; off >>= 1) {
      u64 o = shfl_down_u64(key, off);
      key = key < o ? key : o;
    }
    if ((t & 63) == 0) WMIN[t >> 6] = key;
    __syncthreads();
    if (t == 0) {
      u64 kmin = WMIN[0];
#pragma unroll
      for (int w = 1; w < 4; w++) kmin = kmin < WMIN[w] ? kmin : WMIN[w];
      int l = (int)(kmin & 0xffffffffu);
      float d = __uint_as_float((u32)(kmin >> 32));
      DIST[l] = __builtin_inff();
      float px = ldg1<ISB>(p, (b * Lx + l) * 2 + 0);
      float py = ldg1<ISB>(p, (b * Lx + l) * 2 + 1);
      float s  = ldg1<ISB>(sig, b * Lx + l);
      sm.IDX[kk] = l;
      sm.INVS[kk * 2 + 0] = qx - px;
      sm.INVS[kk * 2 + 1] = qy - py;
      sm.GWS[kk] = (-0.5f * (d * d)) / (s * s);
    }
    __syncthreads();
  }

  if (t < 128) sm.YV[t] = ldg1<ISB>(xh, bid * 128 + t);
  __syncthreads();
  float hacc = 0.0f;
  if (t < 128) {
    hacc = ldg1<ISB>(cb1, t);
    for (int i = 0; i < 128; i++) hacc += sm.YV[i] * ldg1<ISB>(cw1, i * 128 + t);
    hacc = geluf(hacc);
  }
  {
    float s = hacc, s2 = hacc * hacc;
#pragma unroll
    for (int off = 32; off; off >>= 1) {
      s += __shfl_down(s, off);
      s2 += __shfl_down(s2, off);
    }
    if ((t & 63) == 0) { sm.RED[(t >> 6) * 2] = s; sm.RED[(t >> 6) * 2 + 1] = s2; }
  }
  __syncthreads();
  {
    float m   = (sm.RED[0] + sm.RED[2]) * (1.0f / 128.0f);
    float var = fmaxf((sm.RED[1] + sm.RED[3]) * (1.0f / 128.0f) - m * m, 0.0f);
    float rstd = rsqrtf(var + 1e-6f);
    if (t < 128) sm.YV[128 + t] = (hacc - m) * rstd * ldg1<ISB>(cls, t) + ldg1<ISB>(clb, t);
  }
  __syncthreads();
  {
    float a = ldg1<ISB>(cb2, t);
    for (int i = 0; i < 128; i++) a += sm.YV[128 + i] * ldg1<ISB>(cw2, i * 256 + t);
    if (t < 128) sm.GV[t] = a; else sm.BT[t - 128] = a;
  }
  __syncthreads();

  {
    int r = t >> 4, c8 = (t & 15) * 8;
    int li = sm.IDX[r];
    ldg8<ISB>(c, (b * Lx + li) * 128 + c8, sm.CG + r * ALD + c8);
  }
  __syncthreads();

#pragma unroll
  for (int pp = 0; pp < 4; pp++) {
    int idx = t + pp * 256;
    int r = idx >> 6, cc = idx & 63;
    float proj = 12.566370614359172f *
                 (sm.INVS[r * 2] * ldg1<ISB>(rffq, cc) +
                  sm.INVS[r * 2 + 1] * ldg1<ISB>(rffq, 64 + cc));
    bufA[r * ALD + cc]      = sinf(proj);
    bufA[r * ALD + 64 + cc] = cosf(proj);
  }
  __syncthreads();
  gemm128<ISB>(bufA, eqw1, 128, eqb1, bufB, 1, t); __syncthreads();
  gemm128<ISB>(bufB, eqw2, 128, eqb2, bufA, 0, t); __syncthreads();

  gemm512<ISB>(sm.CG, wk, bk, sm.KV, t); __syncthreads();

  for (int h = 0; h < 4; h++) {
    gemm128<ISB>(bufA, (const void*)((const char*)wq + (ISB ? 2 : 4) * (size_t)(h * 128)), 512,
                 (const void*)((const char*)bq + (ISB ? 2 : 4) * (size_t)(h * 128)), bufB, 0, t);
    __syncthreads();
    int r = t >> 4, seg = t & 15;
    float s = 0.0f;
    const float* qp = bufB + r * ALD + seg * 8;
    const float* kp = sm.KV + r * KLD + h * 128 + seg * 8;
#pragma unroll
    for (int e = 0; e < 8; e++) s += qp[e] * kp[e];
    sm.RED[r * 16 + seg] = s;
    __syncthreads();
    if (t < 16) {
      float ss = 0.0f;
      for (int e = 0; e < 16; e++) ss += sm.RED[t * 16 + e];
      sm.ATT[t * 4 + h] = ss * 0.08838834764831845f;
    }
    __syncthreads();
  }

  gemm512<ISB>(sm.CG, wv, bv, sm.KV, t); __syncthreads();

#pragma unroll
  for (int pp = 0; pp < 4; pp++) {
    int idx = t + pp * 256;
    int r = idx >> 6, cc = idx & 63;
    float proj = 12.566370614359172f *
                 (sm.INVS[r * 2] * ldg1<ISB>(rffv, cc) +
                  sm.INVS[r * 2 + 1] * ldg1<ISB>(rffv, 64 + cc));
    bufA[r * ALD + cc]      = sinf(proj);
    bufA[r * ALD + 64 + cc] = cosf(proj);
  }
  __syncthreads();
  gemm128<ISB>(bufA, evw1, 128, evb1, bufB, 1, t); __syncthreads();
  gemm128<ISB>(bufB, evw2, 128, evb2, bufA, 0, t); __syncthreads();

#pragma unroll
  for (int pp = 0; pp < 8; pp++) {
    int idx = t + pp * 256;
    int r = idx >> 7, cc = idx & 127;
    bufA[r * ALD + cc] = bufA[r * ALD + cc] * (1.0f + sm.GV[cc]) + sm.BT[cc];
  }
  __syncthreads();
  gemm128<ISB>(bufA, ivw1, 128, ivb1, bufB, 1, t); __syncthreads();
  ln_vecs<16, ISB>(bufB, ALD, ivls, ivlb, sm.YV, sm.RED, t); __syncthreads();

  ivw2_fuse<ISB>(bufB, ivw2, ivb2, sm.KV, 0, t);
  ivw2_fuse<ISB>(bufB, ivw2, ivb2, sm.KV, 8, t);
  __syncthreads();

  for (int pass = 0; pass < 2; pass++) {
    mm_from_kv<ISB>(sm.KV, mw1, mb1, sm.SA, pass * 32, t); __syncthreads();
    ln_vecs<32, ISB>(sm.SA, ALD, mls, mlb, sm.YV, sm.RED, t); __syncthreads();
    mm_to_kv<ISB>(sm.SA, mw2, mb2, sm.KV, pass * 32, t); __syncthreads();
  }

  if (t < 4) {
    float mx = -1e30f;
    for (int r = 0; r < 16; r++) {
      float v = sm.ATT[r * 4 + t] + sm.GWS[r];
      mx = fmaxf(mx, v);
    }
    float ssum = 0.0f;
    float ev[16];
    for (int r = 0; r < 16; r++) {
      float e = expf(sm.ATT[r * 4 + t] + sm.GWS[r] - mx);
      ev[r] = e; ssum += e;
    }
    float inv = 1.0f / fmaxf(ssum, 1e-37f);
    for (int r = 0; r < 16; r++) sm.ATT[r * 4 + t] = ev[r] * inv;
  }
  __syncthreads();

#pragma unroll
  for (int pp = 0; pp < 2; pp++) {
    int j = t + pp * 256;
    int h = j >> 7;
    float s = 0.0f;
    for (int r = 0; r < 16; r++) s += sm.ATT[r * 4 + h] * sm.KV[r * KLD + j];
    sm.YV[j] = s;
  }
  __syncthreads();

  if (t < 128) {
    float s = ldg1<ISB>(bo, t);
    for (int j = 0; j < 512; j++) s += sm.YV[j] * ldg1<ISB>(wo, j * 128 + t);
    stg1<ISB>(outp, bid * 128 + t, s);
  }
}

// ===========================================================================
// ============  SPLIT-bf16 MFMA PATH for fp32 inputs (flag==0)  =============
// ===========================================================================
//
// Round-6 diagnosis: per-CU weight streaming (3.4MB/16-row block, incl. the
// never-counted 768KB fp32 cw1/cw2 GEMV) is the wall. Round-7: G=4 points per
// block (64-row tiles, 1024 blocks) -> weight bytes /4; v pipeline processed
// per head-chunk (VC = 64x128) so mw1/mw2 read once per 64 rows; phase-1
// conditioning MFMA-ized via transposed cw1/cw2 added to the arena; topK is
// wave-local (1 wave per point, candidates in regs, zero barriers) and runs
// concurrently with the cw1 GEMM on the other 4 waves. Math identical
// (split-bf16 GEMMs, fp32 scalar topK/softmax/LN stats).

#define OFF_WQ    0
#define OFF_WK    65536
#define OFF_WV    131072
#define OFF_IVW2  196608
#define OFF_EQW1  327680
#define OFF_EQW2  344064
#define OFF_EVW1  360448
#define OFF_EVW2  376832
#define OFF_IVW1  393216
#define OFF_MW1   409600
#define OFF_MW2   425984
#define OFF_CW1   442368
#define OFF_CW2   458752
#define WT_TOTAL  491520

__device__ __attribute__((aligned(16))) u16 g_wth[WT_TOTAL];
__device__ __attribute__((aligned(16))) u16 g_wtl[WT_TOTAL];

__global__ void k_prep32(
    const void* wq, const void* wk, const void* wv, const void* ivw2,
    const void* eqw1, const void* eqw2, const void* evw1, const void* evw2,
    const void* ivw1, const void* mw1, const void* mw2,
    const void* cw1, const void* cw2,
    const int* __restrict__ flag) {
  if (*flag != 0) return;
  int gid = blockIdx.x * 256 + threadIdx.x;
  const float* src; int N; int local;
  if      (gid < OFF_WK)   { src = (const float*)wq;   N = 512;  local = gid - OFF_WQ; }
  else if (gid < OFF_WV)   { src = (const float*)wk;   N = 512;  local = gid - OFF_WK; }
  else if (gid < OFF_IVW2) { src = (const float*)wv;   N = 512;  local = gid - OFF_WV; }
  else if (gid < OFF_EQW1) { src = (const float*)ivw2; N = 1024; local = gid - OFF_IVW2; }
  else if (gid < OFF_EQW2) { src = (const float*)eqw1; N = 128;  local = gid - OFF_EQW1; }
  else if (gid < OFF_EVW1) { src = (const float*)eqw2; N = 128;  local = gid - OFF_EQW2; }
  else if (gid < OFF_EVW2) { src = (const float*)evw1; N = 128;  local = gid - OFF_EVW1; }
  else if (gid < OFF_IVW1) { src = (const float*)evw2; N = 128;  local = gid - OFF_EVW2; }
  else if (gid < OFF_MW1)  { src = (const float*)ivw1; N = 128;  local = gid - OFF_IVW1; }
  else if (gid < OFF_MW2)  { src = (const float*)mw1;  N = 128;  local = gid - OFF_MW1; }
  else if (gid < OFF_CW1)  { src = (const float*)mw2;  N = 128;  local = gid - OFF_MW2; }
  else if (gid < OFF_CW2)  { src = (const float*)cw1;  N = 128;  local = gid - OFF_CW1; }
  else                     { src = (const float*)cw2;  N = 256;  local = gid - OFF_CW2; }
  int n = local >> 7, k = local & 127;
  float w = src[k * N + n];
  u16 h = f2bf(w);
  g_wth[gid] = h;
  g_wtl[gid] = f2bf(w - bf(h));
}

__device__ __forceinline__ f32x4 mfma16(bf16x8 a, bf16x8 b, f32x4 c) {
  return __builtin_amdgcn_mfma_f32_16x16x32_bf16(a, b, c, 0, 0, 0);
}

// IN-PLACE 64-row GEMM: buf[64][128] = act(buf @ W + bias). 8 waves,
// wave w: rowgroup rg=w&3, coltiles {(w>>2)*4+j}. Internal barrier between
// all A-frag reads and in-place writes. Caller barriers around.
__device__ __attribute__((noinline)) void g64ip(
    u16* bh, u16* bl,
    const u16* wth, const u16* wtl,
    const float* bias, int act, int t) {
  int lane = t & 63, w = t >> 6;
  int r = lane & 15, kg = lane >> 4;
  int rb = (w & 3) * 16;
  bf16x8 ah[4], al[4];
#pragma unroll
  for (int kc = 0; kc < 4; kc++) {
    ah[kc] = *(const bf16x8*)(bh + (rb + r) * LDB + kc * 32 + kg * 8);
    al[kc] = *(const bf16x8*)(bl + (rb + r) * LDB + kc * 32 + kg * 8);
  }
  __syncthreads();
#pragma unroll
  for (int j = 0; j < 4; j++) {
    int cc = ((w >> 2) * 4 + j) * 16 + r;
    f32x4 acc = {0.f, 0.f, 0.f, 0.f};
#pragma unroll
    for (int kc = 0; kc < 4; kc++) {
      bf16x8 bhf = *(const bf16x8*)(wth + cc * 128 + kc * 32 + kg * 8);
      bf16x8 blf = *(const bf16x8*)(wtl + cc * 128 + kc * 32 + kg * 8);
      acc = mfma16(ah[kc], bhf, acc);
      acc = mfma16(ah[kc], blf, acc);
      acc = mfma16(al[kc], bhf, acc);
    }
    float bc = bias[cc];
#pragma unroll
    for (int q_ = 0; q_ < 4; q_++) {
      float v = acc[q_] + bc;
      if (act) v = geluf(v);
      int o = (rb + kg * 4 + q_) * LDB + cc;
      split2(v, bh + o, bl + o);
    }
  }
}

// 64-row GEMM to a separate dst (v chunk): dst = in @ W + bias
__device__ __attribute__((noinline)) void g64s(
    const u16* inh, const u16* inl,
    const u16* wth, const u16* wtl,
    const float* bias, u16* oh, u16* ol, int t) {
  int lane = t & 63, w = t >> 6;
  int r = lane & 15, kg = lane >> 4;
  int rb = (w & 3) * 16;
  bf16x8 ah[4], al[4];
#pragma unroll
  for (int kc = 0; kc < 4; kc++) {
    ah[kc] = *(const bf16x8*)(inh + (rb + r) * LDB + kc * 32 + kg * 8);
    al[kc] = *(const bf16x8*)(inl + (rb + r) * LDB + kc * 32 + kg * 8);
  }
#pragma unroll
  for (int j = 0; j < 4; j++) {
    int cc = ((w >> 2) * 4 + j) * 16 + r;
    f32x4 acc = {0.f, 0.f, 0.f, 0.f};
#pragma unroll
    for (int kc = 0; kc < 4; kc++) {
      bf16x8 bhf = *(const bf16x8*)(wth + cc * 128 + kc * 32 + kg * 8);
      bf16x8 blf = *(const bf16x8*)(wtl + cc * 128 + kc * 32 + kg * 8);
      acc = mfma16(ah[kc], bhf, acc);
      acc = mfma16(ah[kc], blf, acc);
      acc = mfma16(al[kc], bhf, acc);
    }
    float bc = bias[cc];
#pragma unroll
    for (int q_ = 0; q_ < 4; q_++) {
      int o = (rb + kg * 4 + q_) * LDB + cc;
      split2(acc[q_] + bc, oh + o, ol + o);
    }
  }
}

// chunk ivw2 fuse: [ag|ab] = ACT @ ivw2-chunk; VC = VC*(1+ag+bg)+(ab+bb)
// element-disjoint VC update per thread -> no internal barrier needed.
__device__ __attribute__((noinline)) void ivfuse64(
    const u16* inh, const u16* inl,
    const u16* wgh, const u16* wgl, const u16* wbh, const u16* wbl,
    const float* bg, const float* bb,
    u16* vh, u16* vl, int t) {
  int lane = t & 63, w = t >> 6;
  int r = lane & 15, kg = lane >> 4;
  int rb = (w & 3) * 16;
  bf16x8 ah[4], al[4];
#pragma unroll
  for (int kc = 0; kc < 4; kc++) {
    ah[kc] = *(const bf16x8*)(inh + (rb + r) * LDB + kc * 32 + kg * 8);
    al[kc] = *(const bf16x8*)(inl + (rb + r) * LDB + kc * 32 + kg * 8);
  }
#pragma unroll
  for (int j = 0; j < 4; j++) {
    int cc = ((w >> 2) * 4 + j) * 16 + r;
    f32x4 ag = {0.f, 0.f, 0.f, 0.f}, ab = {0.f, 0.f, 0.f, 0.f};
#pragma unroll
    for (int kc = 0; kc < 4; kc++) {
      bf16x8 bgh = *(const bf16x8*)(wgh + cc * 128 + kc * 32 + kg * 8);
      bf16x8 bgl = *(const bf16x8*)(wgl + cc * 128 + kc * 32 + kg * 8);
      bf16x8 bbh = *(const bf16x8*)(wbh + cc * 128 + kc * 32 + kg * 8);
      bf16x8 bbl = *(const bf16x8*)(wbl + cc * 128 + kc * 32 + kg * 8);
      ag = mfma16(ah[kc], bgh, ag);
      ag = mfma16(ah[kc], bgl, ag);
      ag = mfma16(al[kc], bgh, ag);
      ab = mfma16(ah[kc], bbh, ab);
      ab = mfma16(ah[kc], bbl, ab);
      ab = mfma16(al[kc], bbh, ab);
    }
    float bgv = bg[cc], bbv = bb[cc];
#pragma unroll
    for (int q_ = 0; q_ < 4; q_++) {
      int o = (rb + kg * 4 + q_) * LDB + cc;
      float v = bf(vh[o]) + bf(vl[o]);
      float nv = v * (1.f + (ag[q_] + bgv)) + (ab[q_] + bbv);
      split2(nv, vh + o, vl + o);
    }
  }
}

// per-head q.k over 64 rows: wave w does rg=w&3, coltiles {(w>>2)*4+j};
// two waves per rg hold the two col-halves -> combine via RED.
__device__ __attribute__((noinline)) void att_head64(
    int h, const u16* qh, const u16* ql, const u16* ch, const u16* cl,
    const u16* wqh, const u16* wql, const u16* wkh, const u16* wkl,
    const float* bqp, const float* bkp, float* RED, float* ATT, int t) {
  int lane = t & 63, w = t >> 6;
  int r = lane & 15, kg = lane >> 4;
  int rb = (w & 3) * 16, half = w >> 2;
  bf16x8 aqh[4], aql[4], ckh[4], ckl[4];
#pragma unroll
  for (int kc = 0; kc < 4; kc++) {
    aqh[kc] = *(const bf16x8*)(qh + (rb + r) * LDB + kc * 32 + kg * 8);
    aql[kc] = *(const bf16x8*)(ql + (rb + r) * LDB + kc * 32 + kg * 8);
    ckh[kc] = *(const bf16x8*)(ch + (rb + r) * LDB + kc * 32 + kg * 8);
    ckl[kc] = *(const bf16x8*)(cl + (rb + r) * LDB + kc * 32 + kg * 8);
  }
  float pr[4] = {0.f, 0.f, 0.f, 0.f};
#pragma unroll
  for (int j = 0; j < 4; j++) {
    int cc = (half * 4 + j) * 16 + r;
    f32x4 dq = {0.f, 0.f, 0.f, 0.f}, dk = {0.f, 0.f, 0.f, 0.f};
#pragma unroll
    for (int kc = 0; kc < 4; kc++) {
      bf16x8 qh_ = *(const bf16x8*)(wqh + cc * 128 + kc * 32 + kg * 8);
      bf16x8 ql_ = *(const bf16x8*)(wql + cc * 128 + kc * 32 + kg * 8);
      bf16x8 kh_ = *(const bf16x8*)(wkh + cc * 128 + kc * 32 + kg * 8);
      bf16x8 kl_ = *(const bf16x8*)(wkl + cc * 128 + kc * 32 + kg * 8);
      dq = mfma16(aqh[kc], qh_, dq);
      dq = mfma16(aqh[kc], ql_, dq);
      dq = mfma16(aql[kc], qh_, dq);
      dk = mfma16(ckh[kc], kh_, dk);
      dk = mfma16(ckh[kc], kl_, dk);
      dk = mfma16(ckl[kc], kh_, dk);
    }
    float bqv = bqp[cc], bkv = bkp[cc];
#pragma unroll
    for (int q_ = 0; q_ < 4; q_++)
      pr[q_] += (dq[q_] + bqv) * (dk[q_] + bkv);
  }
#pragma unroll
  for (int m = 1; m <= 8; m <<= 1) {
#pragma unroll
    for (int q_ = 0; q_ < 4; q_++) pr[q_] += __shfl_xor(pr[q_], m);
  }
  if (r == 0) {
#pragma unroll
    for (int q_ = 0; q_ < 4; q_++)
      RED[(rb + kg * 4 + q_) + 64 * half] = pr[q_];
  }
  __syncthreads();
  if (t < 64) {
    int row = t;
    ATT[(row >> 4) * 64 + (row & 15) * 4 + h] =
        (RED[row] + RED[64 + row]) * 0.08838834764831845f;
  }
  __syncthreads();
}

// phase1 cw2: GVBT[pt][0..255] = ACT(rows 16..31) @ cw2T + cb2 (rows<4 valid)
__device__ __attribute__((noinline)) void g256gv(
    const u16* inh, const u16* inl,
    const u16* wth, const u16* wtl,
    const float* bias, float* GVBT, int t) {
  int lane = t & 63, w = t >> 6;
  int r = lane & 15, kg = lane >> 4;
  bf16x8 ah[4], al[4];
#pragma unroll
  for (int kc = 0; kc < 4; kc++) {
    ah[kc] = *(const bf16x8*)(inh + r * LDB + kc * 32 + kg * 8);
    al[kc] = *(const bf16x8*)(inl + r * LDB + kc * 32 + kg * 8);
  }
#pragma unroll
  for (int j = 0; j < 2; j++) {
    int cc = (w * 2 + j) * 16 + r;
    f32x4 acc = {0.f, 0.f, 0.f, 0.f};
#pragma unroll
    for (int kc = 0; kc < 4; kc++) {
      bf16x8 bhf = *(const bf16x8*)(wth + cc * 128 + kc * 32 + kg * 8);
      bf16x8 blf = *(const bf16x8*)(wtl + cc * 128 + kc * 32 + kg * 8);
      acc = mfma16(ah[kc], bhf, acc);
      acc = mfma16(ah[kc], blf, acc);
      acc = mfma16(al[kc], bhf, acc);
    }
    float bc = bias[cc];
#pragma unroll
    for (int q_ = 0; q_ < 4; q_++) {
      int row = kg * 4 + q_;
      if (row < 4) GVBT[row * 256 + cc] = acc[q_] + bc;
    }
  }
}

// LayerNorm over 16 hi/lo rows at stride LDB; 512 thr = 32/row, wave-local.
__device__ __attribute__((noinline)) void lnb16(
    u16* bufh, u16* bufl,
    const float* sc, const float* bi, int t) {
  const int EPV = 4;
  int vec = t >> 5, seg = t & 31;
  int cs = ((seg + vec) & 31) * EPV;
  u16* bph = bufh + vec * LDB + cs;
  u16* bpl = bufl + vec * LDB + cs;
  float xv[EPV];
  float s = 0.f, s2 = 0.f;
#pragma unroll
  for (int e = 0; e < EPV; e++) {
    float xf = bf(bph[e]) + bf(bpl[e]);
    xv[e] = xf; s += xf; s2 += xf * xf;
  }
#pragma unroll
  for (int m = 16; m; m >>= 1) {
    s  += __shfl_xor(s, m);
    s2 += __shfl_xor(s2, m);
  }
  float m = s * (1.f / 128.f);
  float var = fmaxf(s2 * (1.f / 128.f) - m * m, 0.f);
  float rstd = rsqrtf(var + 1e-6f);
#pragma unroll
  for (int e = 0; e < EPV; e++) {
    int col = cs + e;
    split2((xv[e] - m) * rstd * sc[col] + bi[col], bph + e, bpl + e);
  }
}

// LayerNorm over 64 hi/lo rows; 8 threads/row (xor<8 stays in-wave).
__device__ __attribute__((noinline)) void ln64(
    u16* bufh, u16* bufl,
    const float* sc, const float* bi, int t) {
  int row = t >> 3, seg = t & 7;
  int cs = ((seg + row) & 7) * 16;
  u16* bph = bufh + row * LDB + cs;
  u16* bpl = bufl + row * LDB + cs;
  float xv[16];
  float s = 0.f, s2 = 0.f;
#pragma unroll
  for (int e = 0; e < 16; e++) {
    float xf = bf(bph[e]) + bf(bpl[e]);
    xv[e] = xf; s += xf; s2 += xf * xf;
  }
#pragma unroll
  for (int m = 1; m <= 4; m <<= 1) {
    s  += __shfl_xor(s, m);
    s2 += __shfl_xor(s2, m);
  }
  float m = s * (1.f / 128.f);
  float var = fmaxf(s2 * (1.f / 128.f) - m * m, 0.f);
  float rstd = rsqrtf(var + 1e-6f);
#pragma unroll
  for (int e = 0; e < 16; e++) {
    int col = cs + e;
    split2((xv[e] - m) * rstd * sc[col] + bi[col], bph + e, bpl + e);
  }
}

struct __align__(16) SMEM4 {
  u16 CGh[64 * LDB], CGl[64 * LDB];    // 34816B: gathered latents (4 pts x 16)
  u16 ACTh[64 * LDB], ACTl[64 * LDB];  // 34816B: activation tile / IVE
  union {
    struct { u16 h[64 * LDB]; u16 l[64 * LDB]; } VC;  // v head-chunk
    float DIST[4096];                                 // phase-0 overlay
  } V;                                 // 34816B
  float GVBT[4][256];                  // 4096B: per-point [g|bt]
  float INVS[128];                     // [pt*32 + rl*2 + c]
  float GWS[64];                       // [pt*16 + rl]
  float ATT[256];                      // [pt*64 + r*4 + h]
  float RED[512];                      // att scratch
  float YO[4][512];                    // 8192B: per-point y
  int   IDX[64];                       // [pt*16 + kk]
};
// total = 120832 B -> 1 block/CU

__global__ __launch_bounds__(512, 2) void k_mfma32(
    const float* __restrict__ x, const float* __restrict__ p,
    const float* __restrict__ c, const float* __restrict__ sig,
    const float* __restrict__ xh,
    const float* __restrict__ rffq, const float* __restrict__ rffv,
    const float* __restrict__ eqb1, const float* __restrict__ eqb2,
    const float* __restrict__ evb1, const float* __restrict__ evb2,
    const float* __restrict__ bq, const float* __restrict__ bk,
    const float* __restrict__ bv,
    const float* __restrict__ cb1,
    const float* __restrict__ cls, const float* __restrict__ clb,
    const float* __restrict__ cb2,
    const float* __restrict__ ivb1,
    const float* __restrict__ ivls, const float* __restrict__ ivlb,
    const float* __restrict__ ivb2,
    const float* __restrict__ mb1,
    const float* __restrict__ mls, const float* __restrict__ mlb,
    const float* __restrict__ mb2,
    const float* __restrict__ wo, const float* __restrict__ bo,
    const int* __restrict__ flag, float* __restrict__ outp) {
  if (*flag != 0) return;
  __shared__ SMEM4 sm;
  int t = threadIdx.x;
  int bid = blockIdx.x;           // 0..1023, 4 points each
  int lane = t & 63, w = t >> 6;

  // ===== phase 0a: DIST for 4 points, xh -> ACT rows 0-3, zero rows 4-15 ===
  float* DIST = sm.V.DIST;
#pragma unroll 1
  for (int e = 0; e < 8; e++) {
    int idx = t + e * 512;
    int pt = idx >> 10, l = idx & 1023;
    int n_g = bid * 4 + pt, b = n_g >> 11;
    float qx = x[n_g * 2 + 0], qy = x[n_g * 2 + 1];
    float px = p[(b * Lx + l) * 2 + 0];
    float py = p[(b * Lx + l) * 2 + 1];
    float dx = qx - px, dy = qy - py;
    float d2 = __fadd_rn(__fmul_rn(dx, dx), __fmul_rn(dy, dy));
    DIST[idx] = __fsqrt_rn(d2);
  }
  {
    int pt = t >> 7, col = t & 127;
    split2(xh[(bid * 4 + pt) * 128 + col],
           sm.ACTh + pt * LDB + col, sm.ACTl + pt * LDB + col);
  }
#pragma unroll 1
  for (int e = 0; e < 3; e++) {
    int ii = t + e * 512;
    int row = 4 + (ii >> 7), col = ii & 127;
    sm.ACTh[row * LDB + col] = 0;
    sm.ACTl[row * LDB + col] = 0;
  }
  __syncthreads();

  // ===== phase 0b: [waves 0-3: wave-local topK per point] ||
  //                 [waves 4-7: cw1 GEMM rows0-15 -> gelu -> rows16-31] =====
  if (w < 4) {
    int pt = w;
    int n_g = bid * 4 + pt, b = n_g >> 11;
    float qx = x[n_g * 2 + 0], qy = x[n_g * 2 + 1];
    u64 keys[16];
#pragma unroll
    for (int e = 0; e < 16; e++) {
      int l = e * 64 + lane;
      keys[e] = (((u64)__float_as_uint(DIST[pt * 1024 + l])) << 32) | (u32)l;
    }
#pragma unroll 1
    for (int kk = 0; kk < Kx; kk++) {
      u64 kmin = keys[0];
#pragma unroll
      for (int e = 1; e < 16; e++) kmin = kmin < keys[e] ? kmin : keys[e];
#pragma unroll
      for (int m = 1; m <= 32; m <<= 1) {
        u64 o = shfl_xor_u64(kmin, m);
        kmin = kmin < o ? kmin : o;
      }
      if (lane == 0) {
        int l = (int)(kmin & 0xffffffffu);
        float d = __uint_as_float((u32)(kmin >> 32));
        float px = p[(b * Lx + l) * 2 + 0];
        float py = p[(b * Lx + l) * 2 + 1];
        float sg = sig[b * Lx + l];
        sm.IDX[pt * 16 + kk] = l;
        sm.INVS[pt * 32 + kk * 2 + 0] = qx - px;
        sm.INVS[pt * 32 + kk * 2 + 1] = qy - py;
        sm.GWS[pt * 16 + kk] = (-0.5f * (d * d)) / (sg * sg);
      }
#pragma unroll
      for (int e = 0; e < 16; e++) if (keys[e] == kmin) keys[e] = ~0ull;
    }
  } else {
    int w4 = w - 4;
    int r = lane & 15, kg = lane >> 4;
    bf16x8 ah[4], al[4];
#pragma unroll
    for (int kc = 0; kc < 4; kc++) {
      ah[kc] = *(const bf16x8*)(sm.ACTh + r * LDB + kc * 32 + kg * 8);
      al[kc] = *(const bf16x8*)(sm.ACTl + r * LDB + kc * 32 + kg * 8);
    }
#pragma unroll
    for (int j = 0; j < 2; j++) {
      int cc = (w4 * 2 + j) * 16 + r;
      f32x4 acc = {0.f, 0.f, 0.f, 0.f};
#pragma unroll
      for (int kc = 0; kc < 4; kc++) {
        bf16x8 bhf = *(const bf16x8*)(g_wth + OFF_CW1 + cc * 128 + kc * 32 + kg * 8);
        bf16x8 blf = *(const bf16x8*)(g_wtl + OFF_CW1 + cc * 128 + kc * 32 + kg * 8);
        acc = mfma16(ah[kc], bhf, acc);
        acc = mfma16(ah[kc], blf, acc);
        acc = mfma16(al[kc], bhf, acc);
      }
      float bc = cb1[cc];
#pragma unroll
      for (int q_ = 0; q_ < 4; q_++) {
        int o = (16 + kg * 4 + q_) * LDB + cc;
        split2(geluf(acc[q_] + bc), sm.ACTh + o, sm.ACTl + o);
      }
    }
  }
  __syncthreads();

  // ===== phase 1b: LN + cw2 -> GVBT =====
  lnb16(sm.ACTh + 16 * LDB, sm.ACTl + 16 * LDB, cls, clb, t);
  __syncthreads();
  g256gv(sm.ACTh + 16 * LDB, sm.ACTl + 16 * LDB,
         g_wth + OFF_CW2, g_wtl + OFF_CW2, cb2, &sm.GVBT[0][0], t);
  __syncthreads();

  // ===== phase 2: CG gather + q-RFF -> ACT =====
  {
    int row = t >> 3, c16 = (t & 7) * 16;
    int li = sm.IDX[row];
    int b = (bid * 4 + (row >> 4)) >> 11;
    const float* cp = c + ((size_t)(b * Lx + li)) * 128 + c16;
#pragma unroll
    for (int j = 0; j < 16; j++)
      split2(cp[j], sm.CGh + row * LDB + c16 + j, sm.CGl + row * LDB + c16 + j);
  }
#pragma unroll 1
  for (int pp = 0; pp < 8; pp++) {
    int idx = t + pp * 512;
    int r = idx >> 6, cc = idx & 63;
    int pt = r >> 4, rl = r & 15;
    float proj = 12.566370614359172f *
                 (sm.INVS[pt * 32 + rl * 2] * rffq[cc] +
                  sm.INVS[pt * 32 + rl * 2 + 1] * rffq[64 + cc]);
    split2(sinf(proj), sm.ACTh + r * LDB + cc,      sm.ACTl + r * LDB + cc);
    split2(cosf(proj), sm.ACTh + r * LDB + 64 + cc, sm.ACTl + r * LDB + 64 + cc);
  }
  __syncthreads();
  g64ip(sm.ACTh, sm.ACTl, g_wth + OFF_EQW1, g_wtl + OFF_EQW1, eqb1, 1, t); __syncthreads();
  g64ip(sm.ACTh, sm.ACTl, g_wth + OFF_EQW2, g_wtl + OFF_EQW2, eqb2, 0, t); __syncthreads();

  // ===== att =====
#pragma unroll 1
  for (int h = 0; h < 4; h++) {
    att_head64(h, sm.ACTh, sm.ACTl, sm.CGh, sm.CGl,
               g_wth + OFF_WQ + h * 16384, g_wtl + OFF_WQ + h * 16384,
               g_wth + OFF_WK + h * 16384, g_wtl + OFF_WK + h * 16384,
               bq + h * 128, bk + h * 128, sm.RED, sm.ATT, t);
  }

  // ===== softmax over K per (pt, h) =====
  if (t < 16) {
    int pt = t >> 2, hh = t & 3;
    float mx = -1e30f;
    for (int r = 0; r < 16; r++) {
      float v = sm.ATT[pt * 64 + r * 4 + hh] + sm.GWS[pt * 16 + r];
      mx = fmaxf(mx, v);
    }
    float ssum = 0.0f;
    float ev[16];
    for (int r = 0; r < 16; r++) {
      float e = expf(sm.ATT[pt * 64 + r * 4 + hh] + sm.GWS[pt * 16 + r] - mx);
      ev[r] = e; ssum += e;
    }
    float inv = 1.0f / fmaxf(ssum, 1e-37f);
    for (int r = 0; r < 16; r++) sm.ATT[pt * 64 + r * 4 + hh] = ev[r] * inv;
  }
  __syncthreads();

  // ===== v-RFF -> ACT (qemb dead), ev MLP, conditioning, ivw1, LN =====
#pragma unroll 1
  for (int pp = 0; pp < 8; pp++) {
    int idx = t + pp * 512;
    int r = idx >> 6, cc = idx & 63;
    int pt = r >> 4, rl = r & 15;
    float proj = 12.566370614359172f *
                 (sm.INVS[pt * 32 + rl * 2] * rffv[cc] +
                  sm.INVS[pt * 32 + rl * 2 + 1] * rffv[64 + cc]);
    split2(sinf(proj), sm.ACTh + r * LDB + cc,      sm.ACTl + r * LDB + cc);
    split2(cosf(proj), sm.ACTh + r * LDB + 64 + cc, sm.ACTl + r * LDB + 64 + cc);
  }
  __syncthreads();
  g64ip(sm.ACTh, sm.ACTl, g_wth + OFF_EVW1, g_wtl + OFF_EVW1, evb1, 1, t); __syncthreads();
  g64ip(sm.ACTh, sm.ACTl, g_wth + OFF_EVW2, g_wtl + OFF_EVW2, evb2, 0, t); __syncthreads();

#pragma unroll 1
  for (int pp = 0; pp < 16; pp++) {
    int idx = t + pp * 512;
    int r = idx >> 7, cc = idx & 127;
    int pt = r >> 4;
    int o = r * LDB + cc;
    float v = bf(sm.ACTh[o]) + bf(sm.ACTl[o]);
    split2(v * (1.0f + sm.GVBT[pt][cc]) + sm.GVBT[pt][128 + cc],
           sm.ACTh + o, sm.ACTl + o);
  }
  __syncthreads();
  g64ip(sm.ACTh, sm.ACTl, g_wth + OFF_IVW1, g_wtl + OFF_IVW1, ivb1, 1, t); __syncthreads();
  ln64(sm.ACTh, sm.ACTl, ivls, ivlb, t); __syncthreads();

  // ===== v pipeline, one head-chunk at a time =====
#pragma unroll 1
  for (int h = 0; h < 4; h++) {
    g64s(sm.CGh, sm.CGl,
         g_wth + OFF_WV + (h * 128) * 128, g_wtl + OFF_WV + (h * 128) * 128,
         bv + h * 128, sm.V.VC.h, sm.V.VC.l, t);
    __syncthreads();
    ivfuse64(sm.ACTh, sm.ACTl,
             g_wth + OFF_IVW2 + (h * 128) * 128, g_wtl + OFF_IVW2 + (h * 128) * 128,
             g_wth + OFF_IVW2 + (512 + h * 128) * 128, g_wtl + OFF_IVW2 + (512 + h * 128) * 128,
             ivb2 + h * 128, ivb2 + 512 + h * 128,
             sm.V.VC.h, sm.V.VC.l, t);
    __syncthreads();
    g64ip(sm.V.VC.h, sm.V.VC.l, g_wth + OFF_MW1, g_wtl + OFF_MW1, mb1, 1, t); __syncthreads();
    ln64(sm.V.VC.h, sm.V.VC.l, mls, mlb, t); __syncthreads();
    g64ip(sm.V.VC.h, sm.V.VC.l, g_wth + OFF_MW2, g_wtl + OFF_MW2, mb2, 0, t); __syncthreads();
    {
      int pt = t >> 7, d = t & 127;
      float s = 0.0f;
#pragma unroll 4
      for (int r = 0; r < 16; r++) {
        int o = (pt * 16 + r) * LDB + d;
        s += sm.ATT[pt * 64 + r * 4 + h] * (bf(sm.V.VC.h[o]) + bf(sm.V.VC.l[o]));
      }
      sm.YO[pt][h * 128 + d] = s;
    }
    __syncthreads();
  }

  // ===== out = y @ wo + bo =====
  {
    int pt = t >> 7, cc = t & 127;
    float s = bo[cc];
#pragma unroll 8
    for (int j = 0; j < 512; j++) s += sm.YO[pt][j] * wo[j * 128 + cc];
    outp[(bid * 4 + pt) * 128 + cc] = s;
  }
}

// ---------------------------------------------------------------------------
extern "C" void kernel_launch(void* const* d_in, const int* in_sizes, int n_in,
                              void* d_out, int out_size, void* d_ws, size_t ws_size,
                              hipStream_t stream) {
  (void)in_sizes; (void)n_in; (void)out_size; (void)ws_size;
  int* flag = (int*)d_ws;

  k_sniff<<<1, 64, 0, stream>>>(d_in[23], flag);

  // fp32 split-MFMA path (gated on flag==0 inside the kernels)
  k_prep32<<<WT_TOTAL / 256, 256, 0, stream>>>(
      d_in[15], d_in[17], d_in[19], d_in[31],
      d_in[7], d_in[9], d_in[11], d_in[13],
      d_in[27], d_in[33], d_in[37],
      d_in[21], d_in[25], flag);
  k_mfma32<<<Bx * Nx / 4, 512, 0, stream>>>(
      (const float*)d_in[0], (const float*)d_in[1], (const float*)d_in[2],
      (const float*)d_in[3], (const float*)d_in[4], (const float*)d_in[5],
      (const float*)d_in[6],
      (const float*)d_in[8], (const float*)d_in[10],             // eqb1 eqb2
      (const float*)d_in[12], (const float*)d_in[14],            // evb1 evb2
      (const float*)d_in[16], (const float*)d_in[18], (const float*)d_in[20],  // bq bk bv
      (const float*)d_in[22],                                     // cb1
      (const float*)d_in[23], (const float*)d_in[24],             // cls clb
      (const float*)d_in[26],                                     // cb2
      (const float*)d_in[28], (const float*)d_in[29], (const float*)d_in[30],
      (const float*)d_in[32],                                     // ivb1 ivls ivlb ivb2
      (const float*)d_in[34], (const float*)d_in[35], (const float*)d_in[36],
      (const float*)d_in[38],                                     // mb1 mls mlb mb2
      (const float*)d_in[39], (const float*)d_in[40],             // wo bo
      flag, (float*)d_out);

  // bf16 VALU fallback (gated on flag==1)
  k_fused<1><<<Bx * Nx, 256, 0, stream>>>(
      d_in[0], d_in[1], d_in[2], d_in[3], d_in[4], d_in[5], d_in[6],
      d_in[7], d_in[8], d_in[9], d_in[10],
      d_in[11], d_in[12], d_in[13], d_in[14],
      d_in[15], d_in[16], d_in[17], d_in[18], d_in[19], d_in[20],
      d_in[21], d_in[22], d_in[23], d_in[24], d_in[25], d_in[26],
      d_in[27], d_in[28], d_in[29], d_in[30], d_in[31], d_in[32],
      d_in[33], d_in[34], d_in[35], d_in[36], d_in[37], d_in[38],
      d_in[39], d_in[40], flag, d_out);
}